// Round 5
// baseline (213.416 us; speedup 1.0000x reference)
//
#include <hip/hip_runtime.h>

#define IN_F   8192
#define OUT_F  8192
#define NBLK   1024            // 8 rows/block; co-resident (4 blk/CU x 256 CU)
#define W_THRESH 50.0f
#define INHIB  0.5f

typedef float f32x4 __attribute__((ext_vector_type(4)));

// ---------------------------------------------------------------------------
// Single fused kernel. 1024 blocks x 256 threads; each wave owns 2 rows.
//  - spikes staged in LDS (32 KB exactly; round-3 A/B showed removing this
//    costs +3 us by doubling VMEM issue pressure on the states stream)
//  - 268 MB states streamed nontemporal, 2 rows interleaved per wave
//  - current/spike/v_mem/v_th state stays in lane-0 registers
//  - device-wide sum(spikes) via fp32 atomicAdd (exact integers) + a
//    release/acquire counter rendezvous; co-residency guaranteed by
//    __launch_bounds__(256,4) (VGPR<=128 -> 4 blk/CU) + 32 KB LDS (5 blk/CU)
// ---------------------------------------------------------------------------
__global__ __launch_bounds__(256, 4) void snn_fused_kernel(
    const float* __restrict__ spike,
    const float* __restrict__ states,
    const float* __restrict__ v_mem,
    const float* __restrict__ v_th,
    const float* __restrict__ noise,
    float* __restrict__ out,       // [spikes | v_mem_new | v_th_new]
    float* __restrict__ g_total,   // ws + 0,   zeroed each call
    int*   __restrict__ g_count)   // ws + 128, zeroed each call
{
    __shared__ f32x4 s_spike[IN_F / 4];   // 2048 x 16 B = 32 KB exactly

    const int tid = threadIdx.x;

    // stage spikes: 256 threads x 8 float4, coalesced
    {
        const f32x4* sp4 = (const f32x4*)spike;
        #pragma unroll
        for (int k = 0; k < 8; ++k)
            s_spike[tid + k * 256] = sp4[tid + k * 256];
    }
    __syncthreads();

    const int wave = tid >> 6;            // 0..3
    const int lane = tid & 63;
    const int r0   = blockIdx.x * 8 + wave * 2;   // this wave: rows r0, r0+1

    const f32x4* p0 = (const f32x4*)(states + (size_t)r0 * IN_F);
    const f32x4* p1 = p0 + (IN_F / 4);

    float a0 = 0.0f, a1 = 0.0f;
    // 2 rows interleaved: one LDS read feeds both; 8 global loads in flight
    #pragma unroll 4
    for (int j = 0; j < 32; ++j) {
        const int idx = j * 64 + lane;
        const f32x4 sp = s_spike[idx];
        const f32x4 x0 = __builtin_nontemporal_load(p0 + idx);
        const f32x4 x1 = __builtin_nontemporal_load(p1 + idx);
        a0 += (x0[0] > W_THRESH) ? sp[0] : 0.0f;
        a0 += (x0[1] > W_THRESH) ? sp[1] : 0.0f;
        a0 += (x0[2] > W_THRESH) ? sp[2] : 0.0f;
        a0 += (x0[3] > W_THRESH) ? sp[3] : 0.0f;
        a1 += (x1[0] > W_THRESH) ? sp[0] : 0.0f;
        a1 += (x1[1] > W_THRESH) ? sp[1] : 0.0f;
        a1 += (x1[2] > W_THRESH) ? sp[2] : 0.0f;
        a1 += (x1[3] > W_THRESH) ? sp[3] : 0.0f;
    }

    // 64-lane butterfly reductions
    #pragma unroll
    for (int off = 32; off >= 1; off >>= 1) {
        a0 += __shfl_down(a0, off, 64);
        a1 += __shfl_down(a1, off, 64);
    }

    // lane 0 of each wave: spike decision for its 2 rows; keep state in regs
    float c0 = 0, c1 = 0, s0 = 0, s1 = 0, vm0 = 0, vm1 = 0, vt0 = 0, vt1 = 0;
    if (lane == 0) {
        c0 = a0;            c1 = a1;
        vm0 = v_mem[r0];    vm1 = v_mem[r0 + 1];
        vt0 = v_th[r0];     vt1 = v_th[r0 + 1];
        const float n0 = noise[r0], n1 = noise[r0 + 1];
        s0 = (vm0 + c0 + n0 >= vt0) ? 1.0f : 0.0f;
        s1 = (vm1 + c1 + n1 >= vt1) ? 1.0f : 0.0f;
        out[r0]     = s0;
        out[r0 + 1] = s1;
    }

    __syncthreads();                    // all waves done reading s_spike
    float* s_f = (float*)s_spike;       // reuse LDS (keeps block at 32 KB)
    if (lane == 0) s_f[wave] = s0 + s1;
    __syncthreads();

    if (tid == 0) {
        const float bsum = s_f[0] + s_f[1] + s_f[2] + s_f[3];  // 0..8, exact
        __hip_atomic_fetch_add(g_total, bsum, __ATOMIC_RELAXED,
                               __HIP_MEMORY_SCOPE_AGENT);
        __hip_atomic_fetch_add(g_count, 1, __ATOMIC_RELEASE,
                               __HIP_MEMORY_SCOPE_AGENT);
        while (__hip_atomic_load(g_count, __ATOMIC_ACQUIRE,
                                 __HIP_MEMORY_SCOPE_AGENT) < NBLK)
            __builtin_amdgcn_s_sleep(2);
        s_f[0] = __hip_atomic_load(g_total, __ATOMIC_RELAXED,
                                   __HIP_MEMORY_SCOPE_AGENT);
    }
    __syncthreads();

    const float inh = s_f[0] * INHIB;
    if (lane == 0) {
        out[OUT_F + r0]     = (vm0 - inh + c0) * (1.0f - s0) * 0.5f;
        out[OUT_F + r0 + 1] = (vm1 - inh + c1) * (1.0f - s1) * 0.5f;
        float t0 = vt0 + (s0 - 0.1f) * 0.01f;
        float t1 = vt1 + (s1 - 0.1f) * 0.01f;
        out[2 * OUT_F + r0]     = fminf(fmaxf(t0, 0.2f), 5.0f);
        out[2 * OUT_F + r0 + 1] = fminf(fmaxf(t1, 0.2f), 5.0f);
    }
}

// ---------------------------------------------------------------------------
extern "C" void kernel_launch(void* const* d_in, const int* in_sizes, int n_in,
                              void* d_out, int out_size, void* d_ws, size_t ws_size,
                              hipStream_t stream)
{
    const float* spike  = (const float*)d_in[0];  // [1, 8192]
    const float* states = (const float*)d_in[1];  // [8192, 8192]
    const float* v_mem  = (const float*)d_in[2];  // [8192]
    const float* v_th   = (const float*)d_in[3];  // [8192]
    const float* noise  = (const float*)d_in[4];  // [8192]
    float* out = (float*)d_out;                   // [3 * 8192]

    float* g_total = (float*)d_ws;                // ws + 0
    int*   g_count = (int*)((char*)d_ws + 128);   // ws + 128 (own cacheline)

    // zero the rendezvous state every call (graph-capturable memset node);
    // makes the kernel independent of leftover workspace contents
    hipMemsetAsync(d_ws, 0, 256, stream);

    snn_fused_kernel<<<NBLK, 256, 0, stream>>>(
        spike, states, v_mem, v_th, noise, out, g_total, g_count);
}

// Round 6
// 46.349 us; speedup vs baseline: 4.6045x; 4.6045x over previous
//
#include <hip/hip_runtime.h>

#define IN_F   8192
#define OUT_F  8192
#define N_BLK  (OUT_F / 4)     // 2048 blocks in kernel 1
#define W_THRESH 50.0f
#define INHIB  0.5f

typedef float f32x4 __attribute__((ext_vector_type(4)));

// ---------------------------------------------------------------------------
// Kernel 1: current[o] = sum_i spike[i] * (state[o][i] > 50), the per-row
// spike decision, and a per-block spike partial sum for kernel 2.
// One wave per output row; 4 rows per 256-thread block.
// Spikes staged in LDS (round-3 A/B: no-LDS was +3.1 us).
// A/B this round: PLAIN loads for states (no nontemporal) — let the 256 MB
// Infinity Cache retain states across graph replays (round-5 counters proved
// ~50% of the 268 MB is L3-resident: FETCH_SIZE was 131 MB).
// ---------------------------------------------------------------------------
__global__ __launch_bounds__(256) void snn_current_kernel(
    const float* __restrict__ spike,
    const float* __restrict__ states,
    const float* __restrict__ v_mem,
    const float* __restrict__ v_th,
    const float* __restrict__ noise,
    float* __restrict__ current,        // ws[0..8191]
    float* __restrict__ out_spikes,     // out[0..8191]
    float* __restrict__ block_partial)  // ws[8192..10239]
{
    __shared__ f32x4 s_spike[IN_F / 4];   // 2048 x 16 B = 32 KB exactly

    const int tid = threadIdx.x;

    // stage spikes: 256 threads x 8 float4 each, coalesced
    {
        const f32x4* sp4 = (const f32x4*)spike;
        #pragma unroll
        for (int k = 0; k < 8; ++k)
            s_spike[tid + k * 256] = sp4[tid + k * 256];
    }
    __syncthreads();

    const int wave = tid >> 6;            // 0..3
    const int lane = tid & 63;
    const int row  = blockIdx.x * 4 + wave;

    const f32x4* row4 = (const f32x4*)(states + (size_t)row * IN_F);

    float acc = 0.0f;
    // 2048 float4 per row / 64 lanes = 32 iterations; lanes adjacent -> coalesced
    #pragma unroll 8
    for (int j = 0; j < 32; ++j) {
        const int idx = j * 64 + lane;
        f32x4 s  = row4[idx];
        f32x4 sp = s_spike[idx];
        acc += (s[0] > W_THRESH) ? sp[0] : 0.0f;
        acc += (s[1] > W_THRESH) ? sp[1] : 0.0f;
        acc += (s[2] > W_THRESH) ? sp[2] : 0.0f;
        acc += (s[3] > W_THRESH) ? sp[3] : 0.0f;
    }

    // 64-lane butterfly reduction
    #pragma unroll
    for (int off = 32; off >= 1; off >>= 1)
        acc += __shfl_down(acc, off, 64);

    __syncthreads();                       // all waves done reading s_spike
    float* s_f = (float*)s_spike;          // reuse LDS for 4 spike flags

    if (lane == 0) {
        const float c = acc;
        const float pot = v_mem[row] + c + noise[row];
        const float s = (pot >= v_th[row]) ? 1.0f : 0.0f;
        current[row]    = c;
        out_spikes[row] = s;
        s_f[wave]       = s;
    }
    __syncthreads();
    if (tid == 0)
        block_partial[blockIdx.x] = s_f[0] + s_f[1] + s_f[2] + s_f[3];
}

// ---------------------------------------------------------------------------
// Kernel 2: v_mem / v_th updates. Each block redundantly reduces the 2048
// per-block partials (8 KB, L2-resident; exact small integers) to get
// sum(spikes) without atomics, then handles its 256-element slice.
// out layout: [spikes(8192) | v_mem_new(8192) | v_th_new(8192)]
// ---------------------------------------------------------------------------
__global__ __launch_bounds__(256) void snn_update_kernel(
    const float* __restrict__ current,
    const float* __restrict__ v_mem,
    const float* __restrict__ v_th,
    const float* __restrict__ spikes,         // == out[0..8191]
    const float* __restrict__ block_partial,  // ws[8192..10239]
    float* __restrict__ out)
{
    __shared__ float s_part[4];

    const int tid = threadIdx.x;

    // sum of 2048 partials: 256 threads x 2 f32x4 each
    const f32x4* bp4 = (const f32x4*)block_partial;
    float local = 0.0f;
    #pragma unroll
    for (int k = 0; k < 2; ++k) {
        f32x4 v = bp4[tid + k * 256];
        local += v[0] + v[1] + v[2] + v[3];
    }
    #pragma unroll
    for (int off = 32; off >= 1; off >>= 1)
        local += __shfl_down(local, off, 64);
    if ((tid & 63) == 0) s_part[tid >> 6] = local;
    __syncthreads();

    const float total = s_part[0] + s_part[1] + s_part[2] + s_part[3];
    const float inhibition = total * INHIB;

    const int o = blockIdx.x * 256 + tid;
    const float s = spikes[o];
    const float vnew = (v_mem[o] - inhibition + current[o]) * (1.0f - s) * 0.5f;
    out[OUT_F + o] = vnew;
    float tnew = v_th[o] + (s - 0.1f) * 0.01f;
    tnew = fminf(fmaxf(tnew, 0.2f), 5.0f);
    out[2 * OUT_F + o] = tnew;
}

// ---------------------------------------------------------------------------
extern "C" void kernel_launch(void* const* d_in, const int* in_sizes, int n_in,
                              void* d_out, int out_size, void* d_ws, size_t ws_size,
                              hipStream_t stream)
{
    const float* spike  = (const float*)d_in[0];  // [1, 8192]
    const float* states = (const float*)d_in[1];  // [8192, 8192]
    const float* v_mem  = (const float*)d_in[2];  // [8192]
    const float* v_th   = (const float*)d_in[3];  // [8192]
    const float* noise  = (const float*)d_in[4];  // [8192]
    float* out = (float*)d_out;                   // [3 * 8192]

    float* current       = (float*)d_ws;          // ws[0..8191]
    float* block_partial = (float*)d_ws + OUT_F;  // ws[8192..10239]

    snn_current_kernel<<<N_BLK, 256, 0, stream>>>(
        spike, states, v_mem, v_th, noise, current, out, block_partial);
    snn_update_kernel<<<OUT_F / 256, 256, 0, stream>>>(
        current, v_mem, v_th, out, block_partial, out);
}

// Round 7
// 45.189 us; speedup vs baseline: 4.7227x; 1.0257x over previous
//
#include <hip/hip_runtime.h>

#define IN_F   8192
#define OUT_F  8192
#define N_BLK  (OUT_F / 4)     // 2048 blocks in kernel 1
#define W_THRESH 50.0f
#define INHIB  0.5f

typedef float f32x4 __attribute__((ext_vector_type(4)));

// ---------------------------------------------------------------------------
// Kernel 1: current[o] = sum_i spike[i] * (state[o][i] > 50), per-row spike
// decision, and a per-block spike partial for kernel 2.
// One wave per output row; 4 rows per 256-thread block.
// A/B this round: spikes preloaded into REGISTERS (f32x4 sp[32], 128 VGPR,
// coalesced same index map as the states stream, L1/L2-hot) so the inner
// loop is a PURE global-load stream — no ds_read / lgkmcnt waits that could
// bubble VMEM issue. (Round-3's no-LDS failed because spikes were re-read
// from global inside the loop; here they're hoisted.)
// ---------------------------------------------------------------------------
__global__ __launch_bounds__(256) void snn_current_kernel(
    const float* __restrict__ spike,
    const float* __restrict__ states,
    const float* __restrict__ v_mem,
    const float* __restrict__ v_th,
    const float* __restrict__ noise,
    float* __restrict__ current,        // ws[0..8191]
    float* __restrict__ out_spikes,     // out[0..8191]
    float* __restrict__ block_partial)  // ws[8192..10239]
{
    __shared__ float s_f[4];            // 16 B cross-wave scratch only

    const int tid  = threadIdx.x;
    const int wave = tid >> 6;          // 0..3
    const int lane = tid & 63;
    const int row  = blockIdx.x * 4 + wave;

    const f32x4* sp4  = (const f32x4*)spike;
    const f32x4* row4 = (const f32x4*)(states + (size_t)row * IN_F);

    // preload this lane's 32 spike fragments (coalesced: lanes adjacent),
    // fully static indexing -> stays in VGPRs (128 regs)
    f32x4 sp[32];
    #pragma unroll
    for (int j = 0; j < 32; ++j)
        sp[j] = sp4[j * 64 + lane];

    float acc = 0.0f;
    // pure global stream: 32 coalesced dwordx4 per lane, no LDS in loop
    #pragma unroll
    for (int j = 0; j < 32; ++j) {
        const f32x4 s = row4[j * 64 + lane];
        acc += (s[0] > W_THRESH) ? sp[j][0] : 0.0f;
        acc += (s[1] > W_THRESH) ? sp[j][1] : 0.0f;
        acc += (s[2] > W_THRESH) ? sp[j][2] : 0.0f;
        acc += (s[3] > W_THRESH) ? sp[j][3] : 0.0f;
    }

    // 64-lane butterfly reduction
    #pragma unroll
    for (int off = 32; off >= 1; off >>= 1)
        acc += __shfl_down(acc, off, 64);

    float s_val = 0.0f;
    if (lane == 0) {
        const float c = acc;
        const float pot = v_mem[row] + c + noise[row];
        s_val = (pot >= v_th[row]) ? 1.0f : 0.0f;
        current[row]    = c;
        out_spikes[row] = s_val;
        s_f[wave]       = s_val;
    }
    __syncthreads();
    if (tid == 0)
        block_partial[blockIdx.x] = s_f[0] + s_f[1] + s_f[2] + s_f[3];
}

// ---------------------------------------------------------------------------
// Kernel 2: v_mem / v_th updates. Each block redundantly reduces the 2048
// per-block partials (8 KB, L2-resident; exact small integers) to get
// sum(spikes) without atomics, then handles its 256-element slice.
// out layout: [spikes(8192) | v_mem_new(8192) | v_th_new(8192)]
// ---------------------------------------------------------------------------
__global__ __launch_bounds__(256) void snn_update_kernel(
    const float* __restrict__ current,
    const float* __restrict__ v_mem,
    const float* __restrict__ v_th,
    const float* __restrict__ spikes,         // == out[0..8191]
    const float* __restrict__ block_partial,  // ws[8192..10239]
    float* __restrict__ out)
{
    __shared__ float s_part[4];

    const int tid = threadIdx.x;

    // sum of 2048 partials: 256 threads x 2 f32x4 each
    const f32x4* bp4 = (const f32x4*)block_partial;
    float local = 0.0f;
    #pragma unroll
    for (int k = 0; k < 2; ++k) {
        f32x4 v = bp4[tid + k * 256];
        local += v[0] + v[1] + v[2] + v[3];
    }
    #pragma unroll
    for (int off = 32; off >= 1; off >>= 1)
        local += __shfl_down(local, off, 64);
    if ((tid & 63) == 0) s_part[tid >> 6] = local;
    __syncthreads();

    const float total = s_part[0] + s_part[1] + s_part[2] + s_part[3];
    const float inhibition = total * INHIB;

    const int o = blockIdx.x * 256 + tid;
    const float s = spikes[o];
    const float vnew = (v_mem[o] - inhibition + current[o]) * (1.0f - s) * 0.5f;
    out[OUT_F + o] = vnew;
    float tnew = v_th[o] + (s - 0.1f) * 0.01f;
    tnew = fminf(fmaxf(tnew, 0.2f), 5.0f);
    out[2 * OUT_F + o] = tnew;
}

// ---------------------------------------------------------------------------
extern "C" void kernel_launch(void* const* d_in, const int* in_sizes, int n_in,
                              void* d_out, int out_size, void* d_ws, size_t ws_size,
                              hipStream_t stream)
{
    const float* spike  = (const float*)d_in[0];  // [1, 8192]
    const float* states = (const float*)d_in[1];  // [8192, 8192]
    const float* v_mem  = (const float*)d_in[2];  // [8192]
    const float* v_th   = (const float*)d_in[3];  // [8192]
    const float* noise  = (const float*)d_in[4];  // [8192]
    float* out = (float*)d_out;                   // [3 * 8192]

    float* current       = (float*)d_ws;          // ws[0..8191]
    float* block_partial = (float*)d_ws + OUT_F;  // ws[8192..10239]

    snn_current_kernel<<<N_BLK, 256, 0, stream>>>(
        spike, states, v_mem, v_th, noise, current, out, block_partial);
    snn_update_kernel<<<OUT_F / 256, 256, 0, stream>>>(
        current, v_mem, v_th, out, block_partial, out);
}